// Round 2
// baseline (1526.669 us; speedup 1.0000x reference)
//
#include <hip/hip_runtime.h>
#include <cstdint>
#include <cstddef>

// ---------------- degree / norm ----------------
__global__ void deg_count(const int* __restrict__ col, float* __restrict__ deg, int E) {
    int e = blockIdx.x * blockDim.x + threadIdx.x;
    if (e < E) atomicAdd(&deg[col[e]], 1.0f);
}

__global__ void dinv_fin(float* d1, float* d2, int n) {
    int i = blockIdx.x * blockDim.x + threadIdx.x;
    if (i < n) {
        float a = d1[i]; d1[i] = a > 0.f ? rsqrtf(a) : 0.f;
        float b = d2[i]; d2[i] = b > 0.f ? rsqrtf(b) : 0.f;
    }
}

// ---------------- init dest rows with per-half bias ----------------
__global__ void init_bias(float* __restrict__ dest, const float* __restrict__ bA,
                          const float* __restrict__ bB, int total) {
    int i = blockIdx.x * blockDim.x + threadIdx.x;
    if (i < total) {
        int c = i & 127;
        dest[i] = (c < 64) ? bA[c] : bB[c - 64];
    }
}

// ---------------- dense matmul: C[n x 64] = act(A[n x K] @ W[K x 64] (+bias)) ----------------
// block = 256 threads, tile = 64 rows x 64 cols, K chunked by 64.
template <int K, bool RELU>
__global__ __launch_bounds__(256) void mm64(const float* __restrict__ A, const float* __restrict__ W,
                                            const float* __restrict__ bias, float* __restrict__ C,
                                            int n) {
    __shared__ float As[64][65];
    __shared__ float Ws[K][64];
    const int tid = threadIdx.x;
    const int r0 = blockIdx.x * 64;

    for (int idx = tid; idx < K * 64; idx += 256)
        Ws[idx >> 6][idx & 63] = W[idx];

    const int tr = (tid >> 4) * 4;
    const int tc = (tid & 15) * 4;
    float acc[4][4] = {};

    for (int kb = 0; kb < K; kb += 64) {
        __syncthreads();  // first pass: also covers Ws writes
        for (int idx = tid; idx < 64 * 64; idx += 256) {
            int r = idx >> 6, k = idx & 63;
            int gr = r0 + r;
            As[r][k] = (gr < n) ? A[(size_t)gr * K + kb + k] : 0.f;
        }
        __syncthreads();
        for (int k = 0; k < 64; ++k) {
            float a[4], b[4];
#pragma unroll
            for (int i = 0; i < 4; i++) a[i] = As[tr + i][k];
#pragma unroll
            for (int j = 0; j < 4; j++) b[j] = Ws[kb + k][tc + j];
#pragma unroll
            for (int i = 0; i < 4; i++)
#pragma unroll
                for (int j = 0; j < 4; j++) acc[i][j] = fmaf(a[i], b[j], acc[i][j]);
        }
    }

#pragma unroll
    for (int i = 0; i < 4; i++) {
        int gr = r0 + tr + i;
        if (gr < n) {
#pragma unroll
            for (int j = 0; j < 4; j++) {
                float v = acc[i][j];
                if (bias) v += bias[tc + j];
                if (RELU) v = fmaxf(v, 0.f);
                C[(size_t)gr * 64 + tc + j] = v;
            }
        }
    }
}

// ---------------- edge scatter: dest[col, coff + c] += dinv[row]*dinv[col]*Y[row, c] ----------------
// one wave (64 lanes) per edge, lane = channel. dest has row stride 128.
__global__ void scatter64(const int* __restrict__ rowi, const int* __restrict__ coli,
                          const float* __restrict__ dinv, const float* __restrict__ Y,
                          float* __restrict__ dest, int coff, int E) {
    int t = blockIdx.x * blockDim.x + threadIdx.x;
    int e = t >> 6;
    if (e < E) {
        int c = t & 63;
        int r = rowi[e], d = coli[e];
        float nrm = dinv[r] * dinv[d];
        atomicAdd(&dest[d * 128 + coff + c], nrm * Y[r * 64 + c]);
    }
}

// ---------------- readout: out += w * (R @ Wr + br); one wave per node ----------------
// mode 0: store to outacc; 1: accumulate into outacc; 2: accumulate + emit to out
template <int K>
__global__ void readout(const float* __restrict__ R, const float* __restrict__ Wr,
                        const float* __restrict__ br, const float* __restrict__ w,
                        float* __restrict__ outacc, float* __restrict__ outf, int n, int mode) {
    int g = blockIdx.x * blockDim.x + threadIdx.x;
    int node = g >> 6;
    int lane = g & 63;
    if (node >= n) return;
    float v = R[(size_t)node * K + lane] * Wr[lane];
    if (K == 128) v += R[(size_t)node * K + 64 + lane] * Wr[64 + lane];
#pragma unroll
    for (int off = 32; off > 0; off >>= 1) v += __shfl_down(v, off);
    if (lane == 0) {
        float t = (v + br[0]) * w[0];
        if (mode == 0) outacc[node] = t;
        else if (mode == 1) outacc[node] += t;
        else outf[node] = outacc[node] + t;
    }
}

// ---------------- host ----------------
static inline char* carve(char*& p, size_t bytes) {
    char* r = p;
    p += (bytes + 255) & ~(size_t)255;
    return r;
}

extern "C" void kernel_launch(void* const* d_in, const int* in_sizes, int n_in,
                              void* d_out, int out_size, void* d_ws, size_t ws_size,
                              hipStream_t stream) {
    const float* x    = (const float*)d_in[0];
    const int*   ei1  = (const int*)d_in[1];
    const int*   ei2  = (const int*)d_in[2];
    const float* W_in = (const float*)d_in[3];  const float* b_in = (const float*)d_in[4];
    const float* W11  = (const float*)d_in[5];  const float* b11  = (const float*)d_in[6];
    const float* W12  = (const float*)d_in[7];  const float* b12  = (const float*)d_in[8];
    const float* W21  = (const float*)d_in[9];  const float* b21  = (const float*)d_in[10];
    const float* W22  = (const float*)d_in[11]; const float* b22  = (const float*)d_in[12];
    const float* W31  = (const float*)d_in[13]; const float* b31  = (const float*)d_in[14];
    const float* W32  = (const float*)d_in[15]; const float* b32  = (const float*)d_in[16];
    const float* Wr0  = (const float*)d_in[17]; const float* br0  = (const float*)d_in[18];
    const float* Wr1  = (const float*)d_in[19]; const float* br1  = (const float*)d_in[20];
    const float* Wr2  = (const float*)d_in[21]; const float* br2  = (const float*)d_in[22];
    const float* Wr3  = (const float*)d_in[23]; const float* br3  = (const float*)d_in[24];
    const float* w0   = (const float*)d_in[25];
    const float* w1   = (const float*)d_in[26];
    const float* w2   = (const float*)d_in[27];
    const float* w3   = (const float*)d_in[28];

    const int N  = in_sizes[0] / 64;   // 50000
    const int E1 = in_sizes[1] / 2;    // 800000
    const int E2 = in_sizes[2] / 2;

    // workspace carve (~65 MiB): dinv1, dinv2, R0slab[N*64], P[N*128], Q[N*128], outacc[N]
    // Aliasing: layer-1 Y lives in Q's slot (Q not yet initialized);
    //           layer-2/3 Y lives in R0's slot (R0 dead after layer 1).
    char* p = (char*)d_ws;
    float* dinv1  = (float*)carve(p, (size_t)N * 4);
    float* dinv2  = (float*)carve(p, (size_t)N * 4);
    float* R0     = (float*)carve(p, (size_t)N * 64 * 4);
    float* P      = (float*)carve(p, (size_t)N * 128 * 4);
    float* Q      = (float*)carve(p, (size_t)N * 128 * 4);
    float* outacc = (float*)carve(p, (size_t)N * 4);
    float* Y1  = Q;    // layer-1 scratch (first N*64 floats of Q's slot)
    float* Y23 = R0;   // layer-2/3 scratch (R0 dead by then)
    (void)ws_size; (void)n_in; (void)out_size;

    const int B = 256;
    dim3 blk(B);
    int gN    = (N + B - 1) / B;
    int gE1   = (E1 + B - 1) / B;
    int gE2   = (E2 + B - 1) / B;
    int gMM   = (N + 63) / 64;
    int gInit = (N * 128 + B - 1) / B;
    int gRO   = (N * 64 + B - 1) / B;   // one wave per node
    int gSc1  = (int)(((long long)E1 * 64 + B - 1) / B);
    int gSc2  = (int)(((long long)E2 * 64 + B - 1) / B);

    // ---- edge norms ----
    hipMemsetAsync(dinv1, 0, (size_t)N * 4, stream);
    hipMemsetAsync(dinv2, 0, (size_t)N * 4, stream);
    deg_count<<<gE1, blk, 0, stream>>>(ei1 + E1, dinv1, E1);
    deg_count<<<gE2, blk, 0, stream>>>(ei2 + E2, dinv2, E2);
    dinv_fin<<<gN, blk, 0, stream>>>(dinv1, dinv2, N);

    // ---- R0 = relu(x @ W_in + b_in) ----
    mm64<64, true><<<gMM, blk, 0, stream>>>(x, W_in, b_in, R0, N);
    readout<64><<<gRO, blk, 0, stream>>>(R0, Wr0, br0, w0, outacc, nullptr, N, 0);

    // ---- layer 1: R1 (in P) ----
    init_bias<<<gInit, blk, 0, stream>>>(P, b11, b12, N * 128);
    mm64<64, false><<<gMM, blk, 0, stream>>>(R0, W11, nullptr, Y1, N);
    scatter64<<<gSc1, blk, 0, stream>>>(ei1, ei1 + E1, dinv1, Y1, P, 0, E1);
    mm64<64, false><<<gMM, blk, 0, stream>>>(R0, W12, nullptr, Y1, N);
    scatter64<<<gSc2, blk, 0, stream>>>(ei2, ei2 + E2, dinv2, Y1, P, 64, E2);
    readout<128><<<gRO, blk, 0, stream>>>(P, Wr1, br1, w1, outacc, nullptr, N, 1);

    // ---- layer 2: R2 (in Q) ----  (Y1 in Q's slot is dead now; init_bias overwrites)
    init_bias<<<gInit, blk, 0, stream>>>(Q, b21, b22, N * 128);
    mm64<128, false><<<gMM, blk, 0, stream>>>(P, W21, nullptr, Y23, N);
    scatter64<<<gSc1, blk, 0, stream>>>(ei1, ei1 + E1, dinv1, Y23, Q, 0, E1);
    mm64<128, false><<<gMM, blk, 0, stream>>>(P, W22, nullptr, Y23, N);
    scatter64<<<gSc2, blk, 0, stream>>>(ei2, ei2 + E2, dinv2, Y23, Q, 64, E2);
    readout<128><<<gRO, blk, 0, stream>>>(Q, Wr2, br2, w2, outacc, nullptr, N, 1);

    // ---- layer 3: R3 (in P, overwrites R1 which is dead) ----
    init_bias<<<gInit, blk, 0, stream>>>(P, b31, b32, N * 128);
    mm64<128, false><<<gMM, blk, 0, stream>>>(Q, W31, nullptr, Y23, N);
    scatter64<<<gSc1, blk, 0, stream>>>(ei1, ei1 + E1, dinv1, Y23, P, 0, E1);
    mm64<128, false><<<gMM, blk, 0, stream>>>(Q, W32, nullptr, Y23, N);
    scatter64<<<gSc2, blk, 0, stream>>>(ei2, ei2 + E2, dinv2, Y23, P, 64, E2);
    readout<128><<<gRO, blk, 0, stream>>>(P, Wr3, br3, w3, outacc, (float*)d_out, N, 2);
}

// Round 3
// 831.168 us; speedup vs baseline: 1.8368x; 1.8368x over previous
//
#include <hip/hip_runtime.h>
#include <cstdint>
#include <cstddef>

// ================= CSR build =================

// count in-degrees into concat int array: set at [base, base+N)
__global__ void degcnt(const int* __restrict__ col, int* __restrict__ degc, int base, int E) {
    int e = blockIdx.x * blockDim.x + threadIdx.x;
    if (e < E) atomicAdd(&degc[base + col[e]], 1);
}

// dinv{1,2}[i] = rsqrt(degc) (0 if deg==0)
__global__ void dinv_fin(const int* __restrict__ degc, float* __restrict__ d1,
                         float* __restrict__ d2, int n) {
    int i = blockIdx.x * blockDim.x + threadIdx.x;
    if (i < n) {
        int a = degc[i], b = degc[n + i];
        d1[i] = a > 0 ? rsqrtf((float)a) : 0.f;
        d2[i] = b > 0 ? rsqrtf((float)b) : 0.f;
    }
}

// ---- 3-pass exclusive scan over n2 ints (n2 <= 512*256) ----
__global__ void scan1(const int* __restrict__ deg, int* __restrict__ partial, int n) {
    __shared__ int s[256];
    int i = blockIdx.x * 256 + threadIdx.x;
    s[threadIdx.x] = (i < n) ? deg[i] : 0;
    __syncthreads();
    for (int off = 128; off > 0; off >>= 1) {
        if (threadIdx.x < off) s[threadIdx.x] += s[threadIdx.x + off];
        __syncthreads();
    }
    if (threadIdx.x == 0) partial[blockIdx.x] = s[0];
}

__global__ void scan2(int* __restrict__ partial, int nb, int* __restrict__ starts, int n) {
    __shared__ int s[512];
    int t = threadIdx.x;
    int v = (t < nb) ? partial[t] : 0;
    s[t] = v;
    __syncthreads();
    for (int off = 1; off < 512; off <<= 1) {
        int u = (t >= off) ? s[t - off] : 0;
        __syncthreads();
        s[t] += u;
        __syncthreads();
    }
    if (t < nb) partial[t] = s[t] - v;      // exclusive block offsets
    if (t == 511) starts[n] = s[511];       // grand total = E1+E2
}

__global__ void scan3(const int* __restrict__ deg, const int* __restrict__ partial,
                      int* __restrict__ starts, int n) {
    __shared__ int s[256];
    int i = blockIdx.x * 256 + threadIdx.x;
    int v = (i < n) ? deg[i] : 0;
    s[threadIdx.x] = v;
    __syncthreads();
    for (int off = 1; off < 256; off <<= 1) {
        int u = (threadIdx.x >= off) ? s[threadIdx.x - off] : 0;
        __syncthreads();
        s[threadIdx.x] += u;
        __syncthreads();
    }
    if (i < n) starts[i] = partial[blockIdx.x] + s[threadIdx.x] - v;  // exclusive
}

// fill CSR slots: csr[pos] = {src_row, weight = dinv[row]*dinv[col]}
__global__ void csr_fill(const int* __restrict__ rows, const int* __restrict__ cols,
                         const float* __restrict__ dinv, const int* __restrict__ starts,
                         int* __restrict__ cursor, int2* __restrict__ csr, int base, int E) {
    int e = blockIdx.x * blockDim.x + threadIdx.x;
    if (e < E) {
        int r = rows[e], c = cols[e];
        int pos = starts[base + c] + atomicAdd(&cursor[base + c], 1);
        float w = dinv[r] * dinv[c];
        csr[pos] = make_int2(r, __float_as_int(w));
    }
}

// ================= dense matmul: C[n x 64] = act(A[n x K] @ W[K x 64] (+bias)) =================
template <int K, bool RELU>
__global__ __launch_bounds__(256) void mm64(const float* __restrict__ A, const float* __restrict__ W,
                                            const float* __restrict__ bias, float* __restrict__ C,
                                            int n) {
    __shared__ float As[64][65];
    __shared__ float Ws[K][64];
    const int tid = threadIdx.x;
    const int r0 = blockIdx.x * 64;

    for (int idx = tid; idx < K * 64; idx += 256)
        Ws[idx >> 6][idx & 63] = W[idx];

    const int tr = (tid >> 4) * 4;
    const int tc = (tid & 15) * 4;
    float acc[4][4] = {};

    for (int kb = 0; kb < K; kb += 64) {
        __syncthreads();
        for (int idx = tid; idx < 64 * 64; idx += 256) {
            int r = idx >> 6, k = idx & 63;
            int gr = r0 + r;
            As[r][k] = (gr < n) ? A[(size_t)gr * K + kb + k] : 0.f;
        }
        __syncthreads();
        for (int k = 0; k < 64; ++k) {
            float a[4], b[4];
#pragma unroll
            for (int i = 0; i < 4; i++) a[i] = As[tr + i][k];
#pragma unroll
            for (int j = 0; j < 4; j++) b[j] = Ws[kb + k][tc + j];
#pragma unroll
            for (int i = 0; i < 4; i++)
#pragma unroll
                for (int j = 0; j < 4; j++) acc[i][j] = fmaf(a[i], b[j], acc[i][j]);
        }
    }

#pragma unroll
    for (int i = 0; i < 4; i++) {
        int gr = r0 + tr + i;
        if (gr < n) {
#pragma unroll
            for (int j = 0; j < 4; j++) {
                float v = acc[i][j];
                if (bias) v += bias[tc + j];
                if (RELU) v = fmaxf(v, 0.f);
                C[(size_t)gr * 64 + tc + j] = v;
            }
        }
    }
}

// ================= gather aggregation =================
// one wave per dest node; lane = channel. dest[d,coff+c] = bias[c] + sum_e wt_e * Y[src_e, c]
__global__ __launch_bounds__(256) void gather64(const int* __restrict__ starts,
                                                const int2* __restrict__ csr,
                                                const float* __restrict__ Y,
                                                const float* __restrict__ bias,
                                                float* __restrict__ dest, int base, int coff, int N) {
    int wid = (blockIdx.x * blockDim.x + threadIdx.x) >> 6;
    int lane = threadIdx.x & 63;
    if (wid >= N) return;
    int s0 = __builtin_amdgcn_readfirstlane(starts[base + wid]);
    int s1 = __builtin_amdgcn_readfirstlane(starts[base + wid + 1]);
    float acc = 0.f;
    for (int j = s0; j < s1; ++j) {
        int2 ew = csr[j];                       // wave-uniform -> scalar load
        acc += __int_as_float(ew.y) * Y[(size_t)ew.x * 64 + lane];
    }
    dest[(size_t)wid * 128 + coff + lane] = acc + bias[lane];
}

// ================= readout: out += w * (R @ Wr + br) =================
template <int K>
__global__ void readout(const float* __restrict__ R, const float* __restrict__ Wr,
                        const float* __restrict__ br, const float* __restrict__ w,
                        float* __restrict__ outacc, float* __restrict__ outf, int n, int mode) {
    int g = blockIdx.x * blockDim.x + threadIdx.x;
    int node = g >> 6;
    int lane = g & 63;
    if (node >= n) return;
    float v = R[(size_t)node * K + lane] * Wr[lane];
    if (K == 128) v += R[(size_t)node * K + 64 + lane] * Wr[64 + lane];
#pragma unroll
    for (int off = 32; off > 0; off >>= 1) v += __shfl_down(v, off);
    if (lane == 0) {
        float t = (v + br[0]) * w[0];
        if (mode == 0) outacc[node] = t;
        else if (mode == 1) outacc[node] += t;
        else outf[node] = outacc[node] + t;
    }
}

// ================= host =================
static inline char* carve(char*& p, size_t bytes) {
    char* r = p;
    p += (bytes + 255) & ~(size_t)255;
    return r;
}

extern "C" void kernel_launch(void* const* d_in, const int* in_sizes, int n_in,
                              void* d_out, int out_size, void* d_ws, size_t ws_size,
                              hipStream_t stream) {
    const float* x    = (const float*)d_in[0];
    const int*   ei1  = (const int*)d_in[1];
    const int*   ei2  = (const int*)d_in[2];
    const float* W_in = (const float*)d_in[3];  const float* b_in = (const float*)d_in[4];
    const float* W11  = (const float*)d_in[5];  const float* b11  = (const float*)d_in[6];
    const float* W12  = (const float*)d_in[7];  const float* b12  = (const float*)d_in[8];
    const float* W21  = (const float*)d_in[9];  const float* b21  = (const float*)d_in[10];
    const float* W22  = (const float*)d_in[11]; const float* b22  = (const float*)d_in[12];
    const float* W31  = (const float*)d_in[13]; const float* b31  = (const float*)d_in[14];
    const float* W32  = (const float*)d_in[15]; const float* b32  = (const float*)d_in[16];
    const float* Wr0  = (const float*)d_in[17]; const float* br0  = (const float*)d_in[18];
    const float* Wr1  = (const float*)d_in[19]; const float* br1  = (const float*)d_in[20];
    const float* Wr2  = (const float*)d_in[21]; const float* br2  = (const float*)d_in[22];
    const float* Wr3  = (const float*)d_in[23]; const float* br3  = (const float*)d_in[24];
    const float* w0   = (const float*)d_in[25];
    const float* w1   = (const float*)d_in[26];
    const float* w2   = (const float*)d_in[27];
    const float* w3   = (const float*)d_in[28];

    const int N  = in_sizes[0] / 64;   // 50000
    const int E1 = in_sizes[1] / 2;    // 800000
    const int E2 = in_sizes[2] / 2;
    const int N2 = 2 * N;

    // ---- workspace carve (~80 MiB) ----
    char* p = (char*)d_ws;
    float* dinv1  = (float*)carve(p, (size_t)N * 4);
    float* dinv2  = (float*)carve(p, (size_t)N * 4);
    int*   degc   = (int*)  carve(p, (size_t)N2 * 4);
    int*   starts = (int*)  carve(p, ((size_t)N2 + 1) * 4);
    int*   cursor = (int*)  carve(p, (size_t)N2 * 4);
    int*   partial= (int*)  carve(p, 512 * 4);
    int2*  csr    = (int2*) carve(p, (size_t)(E1 + E2) * 8);
    float* R0     = (float*)carve(p, (size_t)N * 64 * 4);
    float* P      = (float*)carve(p, (size_t)N * 128 * 4);
    float* Q      = (float*)carve(p, (size_t)N * 128 * 4);
    float* outacc = (float*)carve(p, (size_t)N * 4);
    float* Y1  = Q;    // layer-1 matmul scratch (Q slot dead until layer 2)
    float* Y23 = R0;   // layer-2/3 matmul scratch (R0 dead after layer-1 readout0... after layer1 mm uses)
    (void)ws_size; (void)n_in; (void)out_size;

    const int B = 256;
    dim3 blk(B);
    int gN   = (N + B - 1) / B;
    int gE1  = (E1 + B - 1) / B;
    int gE2  = (E2 + B - 1) / B;
    int gMM  = (N + 63) / 64;
    int gRO  = (N * 64 + B - 1) / B;    // one wave per node
    int gGa  = (N * 64 + B - 1) / B;    // one wave per dest node
    int nb   = (N2 + 255) / 256;        // scan blocks (<=512)

    // ---- CSR build (both edge sets; concat degree/starts arrays) ----
    hipMemsetAsync(degc, 0, (size_t)N2 * 4, stream);
    hipMemsetAsync(cursor, 0, (size_t)N2 * 4, stream);
    degcnt<<<gE1, blk, 0, stream>>>(ei1 + E1, degc, 0, E1);
    degcnt<<<gE2, blk, 0, stream>>>(ei2 + E2, degc, N, E2);
    dinv_fin<<<gN, blk, 0, stream>>>(degc, dinv1, dinv2, N);
    scan1<<<nb, blk, 0, stream>>>(degc, partial, N2);
    scan2<<<1, 512, 0, stream>>>(partial, nb, starts, N2);
    scan3<<<nb, blk, 0, stream>>>(degc, partial, starts, N2);
    csr_fill<<<gE1, blk, 0, stream>>>(ei1, ei1 + E1, dinv1, starts, cursor, csr, 0, E1);
    csr_fill<<<gE2, blk, 0, stream>>>(ei2, ei2 + E2, dinv2, starts, cursor, csr, N, E2);

    // ---- R0 = relu(x @ W_in + b_in) ----
    mm64<64, true><<<gMM, blk, 0, stream>>>(x, W_in, b_in, R0, N);
    readout<64><<<gRO, blk, 0, stream>>>(R0, Wr0, br0, w0, outacc, nullptr, N, 0);

    // ---- layer 1: R1 (in P) ----
    mm64<64, false><<<gMM, blk, 0, stream>>>(R0, W11, nullptr, Y1, N);
    gather64<<<gGa, blk, 0, stream>>>(starts, csr, Y1, b11, P, 0, 0, N);
    mm64<64, false><<<gMM, blk, 0, stream>>>(R0, W12, nullptr, Y1, N);
    gather64<<<gGa, blk, 0, stream>>>(starts, csr, Y1, b12, P, N, 64, N);
    readout<128><<<gRO, blk, 0, stream>>>(P, Wr1, br1, w1, outacc, nullptr, N, 1);

    // ---- layer 2: R2 (in Q; Y1 region of Q fully overwritten by gathers) ----
    mm64<128, false><<<gMM, blk, 0, stream>>>(P, W21, nullptr, Y23, N);
    gather64<<<gGa, blk, 0, stream>>>(starts, csr, Y23, b21, Q, 0, 0, N);
    mm64<128, false><<<gMM, blk, 0, stream>>>(P, W22, nullptr, Y23, N);
    gather64<<<gGa, blk, 0, stream>>>(starts, csr, Y23, b22, Q, N, 64, N);
    readout<128><<<gRO, blk, 0, stream>>>(Q, Wr2, br2, w2, outacc, nullptr, N, 1);

    // ---- layer 3: R3 (in P, overwrites dead R1) ----
    mm64<128, false><<<gMM, blk, 0, stream>>>(Q, W31, nullptr, Y23, N);
    gather64<<<gGa, blk, 0, stream>>>(starts, csr, Y23, b31, P, 0, 0, N);
    mm64<128, false><<<gMM, blk, 0, stream>>>(Q, W32, nullptr, Y23, N);
    gather64<<<gGa, blk, 0, stream>>>(starts, csr, Y23, b32, P, N, 64, N);
    readout<128><<<gRO, blk, 0, stream>>>(P, Wr3, br3, w3, outacc, (float*)d_out, N, 2);
}

// Round 4
// 627.073 us; speedup vs baseline: 2.4346x; 1.3255x over previous
//
#include <hip/hip_runtime.h>
#include <cstdint>
#include <cstddef>

typedef unsigned short u16;
typedef unsigned int u32;

__device__ __forceinline__ u16 f2b(float f) {
    u32 b = __float_as_uint(f);
    b += 0x7fffu + ((b >> 16) & 1u);   // RNE
    return (u16)(b >> 16);
}
__device__ __forceinline__ float b2f(u16 u) {
    return __uint_as_float(((u32)u) << 16);
}

// ================= CSR build =================
__global__ void degcnt(const int* __restrict__ col, int* __restrict__ degc, int base, int E) {
    int e = blockIdx.x * blockDim.x + threadIdx.x;
    if (e < E) atomicAdd(&degc[base + col[e]], 1);
}

__global__ void dinv_fin(const int* __restrict__ degc, float* __restrict__ d1,
                         float* __restrict__ d2, int n) {
    int i = blockIdx.x * blockDim.x + threadIdx.x;
    if (i < n) {
        int a = degc[i], b = degc[n + i];
        d1[i] = a > 0 ? rsqrtf((float)a) : 0.f;
        d2[i] = b > 0 ? rsqrtf((float)b) : 0.f;
    }
}

__global__ void scan1(const int* __restrict__ deg, int* __restrict__ partial, int n) {
    __shared__ int s[256];
    int i = blockIdx.x * 256 + threadIdx.x;
    s[threadIdx.x] = (i < n) ? deg[i] : 0;
    __syncthreads();
    for (int off = 128; off > 0; off >>= 1) {
        if (threadIdx.x < off) s[threadIdx.x] += s[threadIdx.x + off];
        __syncthreads();
    }
    if (threadIdx.x == 0) partial[blockIdx.x] = s[0];
}

__global__ void scan2(int* __restrict__ partial, int nb, int* __restrict__ starts, int n) {
    __shared__ int s[512];
    int t = threadIdx.x;
    int v = (t < nb) ? partial[t] : 0;
    s[t] = v;
    __syncthreads();
    for (int off = 1; off < 512; off <<= 1) {
        int u = (t >= off) ? s[t - off] : 0;
        __syncthreads();
        s[t] += u;
        __syncthreads();
    }
    if (t < nb) partial[t] = s[t] - v;
    if (t == 511) starts[n] = s[511];
}

__global__ void scan3(const int* __restrict__ deg, const int* __restrict__ partial,
                      int* __restrict__ starts, int n) {
    __shared__ int s[256];
    int i = blockIdx.x * 256 + threadIdx.x;
    int v = (i < n) ? deg[i] : 0;
    s[threadIdx.x] = v;
    __syncthreads();
    for (int off = 1; off < 256; off <<= 1) {
        int u = (threadIdx.x >= off) ? s[threadIdx.x - off] : 0;
        __syncthreads();
        s[threadIdx.x] += u;
        __syncthreads();
    }
    if (i < n) starts[i] = partial[blockIdx.x] + s[threadIdx.x] - v;
}

__global__ void csr_fill(const int* __restrict__ rows, const int* __restrict__ cols,
                         const float* __restrict__ dinv, const int* __restrict__ starts,
                         int* __restrict__ cursor, int2* __restrict__ csr, int base, int E) {
    int e = blockIdx.x * blockDim.x + threadIdx.x;
    if (e < E) {
        int r = rows[e], c = cols[e];
        int pos = starts[base + c] + atomicAdd(&cursor[base + c], 1);
        float w = dinv[r] * dinv[c];
        csr[pos] = make_int2(r, __float_as_int(w));
    }
}

// ================= dense matmul: 64x64 tile, k-vectorized LDS reads =================
// OUT16: write bf16 into C16 (row stride 128, at coff). else fp32 C (row stride 64).
template <int K, bool RELU, bool OUT16>
__global__ __launch_bounds__(256) void mm64(const float* __restrict__ A, const float* __restrict__ W,
                                            const float* __restrict__ bias, float* __restrict__ C,
                                            u16* __restrict__ C16, int coff, int n) {
    __shared__ float As[64][68];   // 68-pad: keeps 16B alignment, 2-way banks
    __shared__ float Ws[K][68];
    const int tid = threadIdx.x;
    const int r0 = blockIdx.x * 64;

    for (int idx = tid; idx < K * 16; idx += 256) {
        int k = idx >> 4, cq = (idx & 15) * 4;
        *(float4*)&Ws[k][cq] = *(const float4*)&W[k * 64 + cq];
    }

    const int tr = (tid >> 4) * 4;
    const int tc = (tid & 15) * 4;
    float4 acc0 = {0, 0, 0, 0}, acc1 = {0, 0, 0, 0}, acc2 = {0, 0, 0, 0}, acc3 = {0, 0, 0, 0};

    for (int kb = 0; kb < K; kb += 64) {
        __syncthreads();  // first pass also covers Ws writes
#pragma unroll
        for (int it = 0; it < 4; ++it) {
            int r = (tid >> 4) + it * 16;
            int cq = (tid & 15) * 4;
            int gr = r0 + r;
            float4 v = {0, 0, 0, 0};
            if (gr < n) v = *(const float4*)&A[(size_t)gr * K + kb + cq];
            *(float4*)&As[r][cq] = v;
        }
        __syncthreads();
#pragma unroll
        for (int k = 0; k < 64; k += 4) {
            float4 a0 = *(const float4*)&As[tr + 0][k];
            float4 a1 = *(const float4*)&As[tr + 1][k];
            float4 a2 = *(const float4*)&As[tr + 2][k];
            float4 a3 = *(const float4*)&As[tr + 3][k];
            float4 b0 = *(const float4*)&Ws[kb + k + 0][tc];
            float4 b1 = *(const float4*)&Ws[kb + k + 1][tc];
            float4 b2 = *(const float4*)&Ws[kb + k + 2][tc];
            float4 b3 = *(const float4*)&Ws[kb + k + 3][tc];
#define DK(comp, B)                                                                 \
            acc0.x = fmaf(a0.comp, B.x, acc0.x); acc0.y = fmaf(a0.comp, B.y, acc0.y); \
            acc0.z = fmaf(a0.comp, B.z, acc0.z); acc0.w = fmaf(a0.comp, B.w, acc0.w); \
            acc1.x = fmaf(a1.comp, B.x, acc1.x); acc1.y = fmaf(a1.comp, B.y, acc1.y); \
            acc1.z = fmaf(a1.comp, B.z, acc1.z); acc1.w = fmaf(a1.comp, B.w, acc1.w); \
            acc2.x = fmaf(a2.comp, B.x, acc2.x); acc2.y = fmaf(a2.comp, B.y, acc2.y); \
            acc2.z = fmaf(a2.comp, B.z, acc2.z); acc2.w = fmaf(a2.comp, B.w, acc2.w); \
            acc3.x = fmaf(a3.comp, B.x, acc3.x); acc3.y = fmaf(a3.comp, B.y, acc3.y); \
            acc3.z = fmaf(a3.comp, B.z, acc3.z); acc3.w = fmaf(a3.comp, B.w, acc3.w);
            DK(x, b0) DK(y, b1) DK(z, b2) DK(w, b3)
#undef DK
        }
    }

    float4 accs[4] = {acc0, acc1, acc2, acc3};
#pragma unroll
    for (int i = 0; i < 4; ++i) {
        int gr = r0 + tr + i;
        if (gr < n) {
            float4 v = accs[i];
            if (!OUT16) {
                if (bias) {
                    float4 bv = *(const float4*)&bias[tc];
                    v.x += bv.x; v.y += bv.y; v.z += bv.z; v.w += bv.w;
                }
                if (RELU) {
                    v.x = fmaxf(v.x, 0.f); v.y = fmaxf(v.y, 0.f);
                    v.z = fmaxf(v.z, 0.f); v.w = fmaxf(v.w, 0.f);
                }
                *(float4*)&C[(size_t)gr * 64 + tc] = v;
            } else {
                ushort4 o;
                o.x = f2b(v.x); o.y = f2b(v.y); o.z = f2b(v.z); o.w = f2b(v.w);
                *(ushort4*)&C16[(size_t)gr * 128 + coff + tc] = o;
            }
        }
    }
}

// ================= merged gather: 2N waves, set1 -> cols 0-63, set2 -> cols 64-127 =================
__global__ __launch_bounds__(256) void gatherB(const int* __restrict__ starts,
                                               const int2* __restrict__ csr,
                                               const u16* __restrict__ Y16,
                                               const float* __restrict__ bA,
                                               const float* __restrict__ bB,
                                               float* __restrict__ dest, int N) {
    int wave = (blockIdx.x * blockDim.x + threadIdx.x) >> 6;
    int lane = threadIdx.x & 63;
    if (wave >= 2 * N) return;
    int set2 = wave >= N;
    int d = set2 ? wave - N : wave;
    int base = set2 ? N : 0;
    int yoff = set2 ? 64 : 0;
    const float* bias = set2 ? bB : bA;

    int s0 = __builtin_amdgcn_readfirstlane(starts[base + d]);
    int s1 = __builtin_amdgcn_readfirstlane(starts[base + d + 1]);

    float acc = 0.f;
    int j = s0;
    for (; j + 4 <= s1; j += 4) {
        int2 e0 = csr[j + 0];
        int2 e1 = csr[j + 1];
        int2 e2 = csr[j + 2];
        int2 e3 = csr[j + 3];
        float y0 = b2f(Y16[(size_t)e0.x * 128 + yoff + lane]);
        float y1 = b2f(Y16[(size_t)e1.x * 128 + yoff + lane]);
        float y2 = b2f(Y16[(size_t)e2.x * 128 + yoff + lane]);
        float y3 = b2f(Y16[(size_t)e3.x * 128 + yoff + lane]);
        acc = fmaf(__int_as_float(e0.y), y0, acc);
        acc = fmaf(__int_as_float(e1.y), y1, acc);
        acc = fmaf(__int_as_float(e2.y), y2, acc);
        acc = fmaf(__int_as_float(e3.y), y3, acc);
    }
    for (; j < s1; ++j) {
        int2 e = csr[j];
        acc = fmaf(__int_as_float(e.y), b2f(Y16[(size_t)e.x * 128 + yoff + lane]), acc);
    }
    dest[(size_t)d * 128 + yoff + lane] = acc + bias[lane];
}

// ================= readout: out += w * (R @ Wr + br) =================
template <int K>
__global__ void readout(const float* __restrict__ R, const float* __restrict__ Wr,
                        const float* __restrict__ br, const float* __restrict__ w,
                        float* __restrict__ outacc, float* __restrict__ outf, int n, int mode) {
    int g = blockIdx.x * blockDim.x + threadIdx.x;
    int node = g >> 6;
    int lane = g & 63;
    if (node >= n) return;
    float v = R[(size_t)node * K + lane] * Wr[lane];
    if (K == 128) v += R[(size_t)node * K + 64 + lane] * Wr[64 + lane];
#pragma unroll
    for (int off = 32; off > 0; off >>= 1) v += __shfl_down(v, off);
    if (lane == 0) {
        float t = (v + br[0]) * w[0];
        if (mode == 0) outacc[node] = t;
        else if (mode == 1) outacc[node] += t;
        else outf[node] = outacc[node] + t;
    }
}

// ================= host =================
static inline char* carve(char*& p, size_t bytes) {
    char* r = p;
    p += (bytes + 255) & ~(size_t)255;
    return r;
}

extern "C" void kernel_launch(void* const* d_in, const int* in_sizes, int n_in,
                              void* d_out, int out_size, void* d_ws, size_t ws_size,
                              hipStream_t stream) {
    const float* x    = (const float*)d_in[0];
    const int*   ei1  = (const int*)d_in[1];
    const int*   ei2  = (const int*)d_in[2];
    const float* W_in = (const float*)d_in[3];  const float* b_in = (const float*)d_in[4];
    const float* W11  = (const float*)d_in[5];  const float* b11  = (const float*)d_in[6];
    const float* W12  = (const float*)d_in[7];  const float* b12  = (const float*)d_in[8];
    const float* W21  = (const float*)d_in[9];  const float* b21  = (const float*)d_in[10];
    const float* W22  = (const float*)d_in[11]; const float* b22  = (const float*)d_in[12];
    const float* W31  = (const float*)d_in[13]; const float* b31  = (const float*)d_in[14];
    const float* W32  = (const float*)d_in[15]; const float* b32  = (const float*)d_in[16];
    const float* Wr0  = (const float*)d_in[17]; const float* br0  = (const float*)d_in[18];
    const float* Wr1  = (const float*)d_in[19]; const float* br1  = (const float*)d_in[20];
    const float* Wr2  = (const float*)d_in[21]; const float* br2  = (const float*)d_in[22];
    const float* Wr3  = (const float*)d_in[23]; const float* br3  = (const float*)d_in[24];
    const float* w0   = (const float*)d_in[25];
    const float* w1   = (const float*)d_in[26];
    const float* w2   = (const float*)d_in[27];
    const float* w3   = (const float*)d_in[28];

    const int N  = in_sizes[0] / 64;   // 50000
    const int E1 = in_sizes[1] / 2;    // 800000
    const int E2 = in_sizes[2] / 2;
    const int N2 = 2 * N;

    char* p = (char*)d_ws;
    float* dinv1   = (float*)carve(p, (size_t)N * 4);
    float* dinv2   = (float*)carve(p, (size_t)N * 4);
    int*   degc    = (int*)  carve(p, (size_t)N2 * 4);
    int*   starts  = (int*)  carve(p, ((size_t)N2 + 1) * 4);
    int*   cursor  = (int*)  carve(p, (size_t)N2 * 4);
    int*   partial = (int*)  carve(p, 512 * 4);
    int2*  csr     = (int2*) carve(p, (size_t)(E1 + E2) * 8);
    float* R0      = (float*)carve(p, (size_t)N * 64 * 4);
    float* P       = (float*)carve(p, (size_t)N * 128 * 4);
    float* Q       = (float*)carve(p, (size_t)N * 128 * 4);
    float* outacc  = (float*)carve(p, (size_t)N * 4);
    // bf16 Y (N x 128 ushort = 12.8 MB) aliases dead fp32 slots:
    u16* Y16_L1  = (u16*)Q;    // layer-1: Q not yet live
    u16* Y16_L23 = (u16*)R0;   // layers 2/3: R0 dead after layer-1 mms
    (void)ws_size; (void)n_in; (void)out_size;

    const int B = 256;
    dim3 blk(B);
    int gN  = (N + B - 1) / B;
    int gE1 = (E1 + B - 1) / B;
    int gE2 = (E2 + B - 1) / B;
    int gMM = (N + 63) / 64;
    int gRO = (N * 64 + B - 1) / B;            // one wave per node
    int gGa = (int)(((long long)N2 * 64 + B - 1) / B);  // 2N waves
    int nb  = (N2 + 255) / 256;

    // ---- CSR build ----
    hipMemsetAsync(degc, 0, (size_t)N2 * 4, stream);
    hipMemsetAsync(cursor, 0, (size_t)N2 * 4, stream);
    degcnt<<<gE1, blk, 0, stream>>>(ei1 + E1, degc, 0, E1);
    degcnt<<<gE2, blk, 0, stream>>>(ei2 + E2, degc, N, E2);
    dinv_fin<<<gN, blk, 0, stream>>>(degc, dinv1, dinv2, N);
    scan1<<<nb, blk, 0, stream>>>(degc, partial, N2);
    scan2<<<1, 512, 0, stream>>>(partial, nb, starts, N2);
    scan3<<<nb, blk, 0, stream>>>(degc, partial, starts, N2);
    csr_fill<<<gE1, blk, 0, stream>>>(ei1, ei1 + E1, dinv1, starts, cursor, csr, 0, E1);
    csr_fill<<<gE2, blk, 0, stream>>>(ei2, ei2 + E2, dinv2, starts, cursor, csr, N, E2);

    // ---- R0 = relu(x @ W_in + b_in) ----
    mm64<64, true, false><<<gMM, blk, 0, stream>>>(x, W_in, b_in, R0, nullptr, 0, N);
    readout<64><<<gRO, blk, 0, stream>>>(R0, Wr0, br0, w0, outacc, nullptr, N, 0);

    // ---- layer 1: R1 (in P) ----
    mm64<64, false, true><<<gMM, blk, 0, stream>>>(R0, W11, nullptr, nullptr, Y16_L1, 0, N);
    mm64<64, false, true><<<gMM, blk, 0, stream>>>(R0, W12, nullptr, nullptr, Y16_L1, 64, N);
    gatherB<<<gGa, blk, 0, stream>>>(starts, csr, Y16_L1, b11, b12, P, N);
    readout<128><<<gRO, blk, 0, stream>>>(P, Wr1, br1, w1, outacc, nullptr, N, 1);

    // ---- layer 2: R2 (in Q; stale Y16 region fully overwritten by gather) ----
    mm64<128, false, true><<<gMM, blk, 0, stream>>>(P, W21, nullptr, nullptr, Y16_L23, 0, N);
    mm64<128, false, true><<<gMM, blk, 0, stream>>>(P, W22, nullptr, nullptr, Y16_L23, 64, N);
    gatherB<<<gGa, blk, 0, stream>>>(starts, csr, Y16_L23, b21, b22, Q, N);
    readout<128><<<gRO, blk, 0, stream>>>(Q, Wr2, br2, w2, outacc, nullptr, N, 1);

    // ---- layer 3: R3 (in P, overwrites dead R1) ----
    mm64<128, false, true><<<gMM, blk, 0, stream>>>(Q, W31, nullptr, nullptr, Y16_L23, 0, N);
    mm64<128, false, true><<<gMM, blk, 0, stream>>>(Q, W32, nullptr, nullptr, Y16_L23, 64, N);
    gatherB<<<gGa, blk, 0, stream>>>(starts, csr, Y16_L23, b31, b32, P, N);
    readout<128><<<gRO, blk, 0, stream>>>(P, Wr3, br3, w3, outacc, (float*)d_out, N, 2);
}